// Round 9
// baseline (3239.606 us; speedup 1.0000x reference)
//
#include <hip/hip_runtime.h>

#define N_VOX 200000
#define K_OFF 27
#define P_PAIR 400000
#define C_IN 32
#define C_MID 64
#define C_OUT 32
#define VT 16
#define NGRP (N_VOX / VT)                 // 12500
#define NBUCK (NGRP * K_OFF)              // 337500 (bucket = group*27 + k)
#define NPAIR_TOT (K_OFF * P_PAIR)        // 10,800,000
#define NSB ((NBUCK + 255) / 256)         // 1319 scan blocks
// tile entry bits: vin[0:18) | local[18:22) | k[22:27) | valid[27]

typedef __attribute__((ext_vector_type(8))) short short8;
typedef __attribute__((ext_vector_type(4))) float f32x4;

__device__ inline short f2bf(float f) {
    union { float f; unsigned u; } v; v.f = f;
    unsigned r = v.u + 0x7FFF + ((v.u >> 16) & 1);   // RNE
    return (short)(r >> 16);
}

// ---------- feats f32 -> bf16 ----------
__global__ __launch_bounds__(256) void cvt_feats(
    const float* __restrict__ in, unsigned short* __restrict__ out)
{
    const int i = blockIdx.x * 256 + threadIdx.x;
    f32x4 v = ((const f32x4*)in)[i];
    ((unsigned int*)out)[2*i]   = (unsigned short)f2bf(v[0]) | ((unsigned)(unsigned short)f2bf(v[1]) << 16);
    ((unsigned int*)out)[2*i+1] = (unsigned short)f2bf(v[2]) | ((unsigned)(unsigned short)f2bf(v[3]) << 16);
}

// ---------- W -> fragment-ordered bf16 tables ----------
__global__ __launch_bounds__(64) void cvt_w(
    const float* __restrict__ W_in, const float* __restrict__ W_out,
    short* __restrict__ Wb1, short* __restrict__ Wb2)
{
    const int b = blockIdx.x, lane = threadIdx.x;
    const int g = lane >> 4, r = lane & 15;
    short8 o;
    if (b < 108) {                                   // conv1: k=b/4, nt=b%4
        const int k = b >> 2, nt = b & 3;
        const float* Wk = W_in + (size_t)k * (C_IN * C_MID);
#pragma unroll
        for (int j = 0; j < 8; ++j) o[j] = f2bf(Wk[(g*8+j)*C_MID + nt*16 + r]);
        *(short8*)(Wb1 + (size_t)(b * 64 + lane) * 8) = o;
    } else {                                         // conv2: q = nt*2+ks
        const int b2 = b - 108, k = b2 >> 2, q = b2 & 3;
        const int nt = q >> 1, ks = q & 1;
        const float* Wk = W_out + (size_t)k * (C_MID * C_OUT);
#pragma unroll
        for (int j = 0; j < 8; ++j) o[j] = f2bf(Wk[(ks*32 + g*8 + j)*C_OUT + nt*16 + r]);
        *(short8*)(Wb2 + (size_t)(b2 * 64 + lane) * 8) = o;
    }
}

// ---------- CSR build ----------
__global__ __launch_bounds__(256) void count_kernel(
    const int* __restrict__ out_idx, const float* __restrict__ mask,
    int* __restrict__ counts)
{
    const int e = blockIdx.x * 256 + threadIdx.x;
    if (e >= NPAIR_TOT) return;
    if (mask[e] > 0.5f) {
        const int k = e / P_PAIR;
        atomicAdd(&counts[(out_idx[e] >> 4) * K_OFF + k], 1);
    }
}

// 3-phase coalesced scan over 16-rounded capacities, group-major order.
__global__ __launch_bounds__(256) void scan_a(
    const int* __restrict__ counts, int* __restrict__ bsum)
{
    __shared__ int s[256];
    const int i = blockIdx.x * 256 + threadIdx.x;
    s[threadIdx.x] = (i < NBUCK) ? ((counts[i] + 15) & ~15) : 0;
    __syncthreads();
    for (int d = 128; d > 0; d >>= 1) {
        if (threadIdx.x < d) s[threadIdx.x] += s[threadIdx.x + d];
        __syncthreads();
    }
    if (threadIdx.x == 0) bsum[blockIdx.x] = s[0];
}

__global__ __launch_bounds__(256) void scan_b(int* __restrict__ bsum)
{
    __shared__ int s[NSB];
    for (int i = threadIdx.x; i < NSB; i += 256) s[i] = bsum[i];
    __syncthreads();
    if (threadIdx.x == 0) {
        int run = 0;
        for (int i = 0; i < NSB; ++i) { const int c = s[i]; s[i] = run; run += c; }
    }
    __syncthreads();
    for (int i = threadIdx.x; i < NSB; i += 256) bsum[i] = s[i];
}

__global__ __launch_bounds__(256) void scan_c(
    const int* __restrict__ counts, const int* __restrict__ bsum,
    int* __restrict__ off, int* __restrict__ cursor)
{
    __shared__ int s[256];
    const int i = blockIdx.x * 256 + threadIdx.x;
    const int c = (i < NBUCK) ? ((counts[i] + 15) & ~15) : 0;
    s[threadIdx.x] = c;
    __syncthreads();
    if (threadIdx.x == 0) {
        int run = bsum[blockIdx.x];
        for (int j = 0; j < 256; ++j) { const int cc = s[j]; s[j] = run; run += cc; }
    }
    __syncthreads();
    if (i < NBUCK) {
        off[i] = s[threadIdx.x]; cursor[i] = s[threadIdx.x];
        if (i == NBUCK - 1) off[NBUCK] = s[threadIdx.x] + c;
    }
}

__global__ __launch_bounds__(256) void fill_kernel(
    const int* __restrict__ in_idx, const int* __restrict__ out_idx,
    const float* __restrict__ mask, int* __restrict__ cursor,
    int* __restrict__ tiles)
{
    const int e = blockIdx.x * 256 + threadIdx.x;
    if (e >= NPAIR_TOT) return;
    if (mask[e] > 0.5f) {
        const int k = e / P_PAIR;
        const int v = out_idx[e];
        const int b = (v >> 4) * K_OFF + k;
        const int pos = atomicAdd(&cursor[b], 1);
        tiles[pos] = in_idx[e] | ((v & 15) << 18) | (k << 22) | (1 << 27);
    }
}

// ---------- conv1: global_load_lds double-buffered gather ----------
// Wave-private staging: tile A-data (16 rows x 64B) lands in LDS linearly:
// slot l (16B) <- featsb[vin(row=l>>2)] chunk (l&3). ds_read_b128 at
// row*64+g*16 then yields the R3-proven A-fragment. Async copy is
// compiler-proof (no dest VGPR); drained with counted vmcnt(2), never 0.
__global__ __launch_bounds__(256, 4) void conv1_tile(
    const unsigned short* __restrict__ featsb, const short* __restrict__ Wb1,
    const int* __restrict__ tiles, const int* __restrict__ off,
    unsigned short* __restrict__ h)
{
    __shared__ float hs[4][VT * 68];                        // 17,408 B
    __shared__ __align__(16) unsigned short stg[4][2][512]; // 4w x 2buf x 1KB
    const int tid = threadIdx.x, lane = tid & 63, wave = tid >> 6;
    const int g = lane >> 4, r = lane & 15;
    const int G = blockIdx.x;
    float* hw = hs[wave];
    for (int i = lane; i < VT * 68; i += 64) hw[i] = 0.f;

    const int t0 = off[G * K_OFF] >> 4;
    const int t1 = off[G * K_OFF + K_OFF] >> 4;

    const int srow = lane >> 2, schk = lane & 3;            // staging map

    const int tA0 = t0 + wave;
    if (tA0 < t1) {
        // prologue: stage tile tA0 into buf0; prefetch entries for tA0+4
        int erA = tiles[(tA0 << 4) + srow];
        __builtin_amdgcn_global_load_lds(
            (const unsigned int*)(featsb + (size_t)(erA & 0x3FFFF) * C_IN + schk * 8),
            (unsigned int*)&stg[wave][0][0], 16, 0, 0);
        const int tB0 = (tA0 + 4 < t1) ? tA0 + 4 : tA0;
        int erB = tiles[(tB0 << 4) + srow];
        int buf = 0;

        for (int t = tA0; t < t1; t += 4) {
            // stage t+4 (clamped) into the other buffer
            __builtin_amdgcn_global_load_lds(
                (const unsigned int*)(featsb + (size_t)(erB & 0x3FFFF) * C_IN + schk * 8),
                (unsigned int*)&stg[wave][buf ^ 1][0], 16, 0, 0);
            // prefetch entries for t+8 (clamped)
            const int tn2 = (t + 8 < t1) ? t + 8 : ((t + 4 < t1) ? t + 4 : t);
            const int erN = tiles[(tn2 << 4) + srow];

            // W fragments for this tile (slot0 always a valid entry)
            const int kk = (__builtin_amdgcn_readfirstlane(erA) >> 22) & 31;
            const short8* wp = (const short8*)Wb1 + (size_t)(kk * 4) * 64 + lane;
            const short8 f0 = wp[0], f1 = wp[64], f2 = wp[128], f3 = wp[192];

            // drain to: {STAGE(t+4), er(t+8)} outstanding -> tile t landed
            asm volatile("s_waitcnt vmcnt(2)" ::: "memory");
            __builtin_amdgcn_sched_barrier(0);

            const short8 a = *(const short8*)&stg[wave][buf][(r * 4 + g) * 8];

            f32x4 acc0 = {}, acc1 = {}, acc2 = {}, acc3 = {};
            acc0 = __builtin_amdgcn_mfma_f32_16x16x32_bf16(a, f0, acc0, 0, 0, 0);
            acc1 = __builtin_amdgcn_mfma_f32_16x16x32_bf16(a, f1, acc1, 0, 0, 0);
            acc2 = __builtin_amdgcn_mfma_f32_16x16x32_bf16(a, f2, acc2, 0, 0, 0);
            acc3 = __builtin_amdgcn_mfma_f32_16x16x32_bf16(a, f3, acc3, 0, 0, 0);

#pragma unroll
            for (int i = 0; i < 4; ++i) {                   // C/D row m=4g+i, col r
                const int rm = tiles[(t << 4) + g * 4 + i]; // L1-hot line
                if ((rm >> 27) & 1) {
                    float* hp = &hw[((rm >> 18) & 15) * 68 + r];
                    atomicAdd(hp +  0, acc0[i]);
                    atomicAdd(hp + 16, acc1[i]);
                    atomicAdd(hp + 32, acc2[i]);
                    atomicAdd(hp + 48, acc3[i]);
                }
            }
            erA = erB; erB = erN; buf ^= 1;
        }
    }

    __syncthreads();
    // reduce 4 slices, ReLU, bf16-pack, coalesced write
    unsigned int* hout = (unsigned int*)(h + (size_t)G * VT * C_MID);
    for (int i = tid; i < VT * C_MID / 2; i += 256) {
        const int e0 = 2 * i;
        const int row = e0 >> 6, col = e0 & 63;
        const int i0 = row * 68 + col;
        const float s0 = hs[0][i0]     + hs[1][i0]     + hs[2][i0]     + hs[3][i0];
        const float s1 = hs[0][i0 + 1] + hs[1][i0 + 1] + hs[2][i0 + 1] + hs[3][i0 + 1];
        const unsigned short lo = (unsigned short)f2bf(fmaxf(s0, 0.f));
        const unsigned short hi = (unsigned short)f2bf(fmaxf(s1, 0.f));
        hout[i] = (unsigned)lo | ((unsigned)hi << 16);
    }
}

// ---------- conv2: same machinery, 128B rows -> 2 staging instrs ----------
__global__ __launch_bounds__(256, 4) void conv2_tile(
    const unsigned short* __restrict__ hb, const short* __restrict__ Wb2,
    const int* __restrict__ tiles, const int* __restrict__ off,
    float* __restrict__ out)
{
    __shared__ float os[4][VT * 36];                         // 9,216 B
    __shared__ __align__(16) unsigned short stg[4][2][1024]; // 4w x 2buf x 2KB
    const int tid = threadIdx.x, lane = tid & 63, wave = tid >> 6;
    const int g = lane >> 4, r = lane & 15;
    const int G = blockIdx.x;
    float* ow = os[wave];
    for (int i = lane; i < VT * 36; i += 64) ow[i] = 0.f;

    const int t0 = off[G * K_OFF] >> 4;
    const int t1 = off[G * K_OFF + K_OFF] >> 4;

    const int srow = lane >> 3, schk = lane & 7;  // instr covers 8 rows x 128B

#define C2_STAGE(BUF, E0, E1)                                                  \
    {                                                                          \
        __builtin_amdgcn_global_load_lds(                                      \
            (const unsigned int*)(hb + (size_t)((E0) & 0x3FFFF) * C_MID + schk * 8), \
            (unsigned int*)&stg[wave][BUF][0], 16, 0, 0);                      \
        __builtin_amdgcn_global_load_lds(                                      \
            (const unsigned int*)(hb + (size_t)((E1) & 0x3FFFF) * C_MID + schk * 8), \
            (unsigned int*)&stg[wave][BUF][512], 16, 0, 0);                    \
    }

    const int tA0 = t0 + wave;
    if (tA0 < t1) {
        int e0A = tiles[(tA0 << 4) + srow];
        int e1A = tiles[(tA0 << 4) + 8 + srow];
        C2_STAGE(0, e0A, e1A);
        const int tB0 = (tA0 + 4 < t1) ? tA0 + 4 : tA0;
        int e0B = tiles[(tB0 << 4) + srow];
        int e1B = tiles[(tB0 << 4) + 8 + srow];
        int buf = 0;

        for (int t = tA0; t < t1; t += 4) {
            C2_STAGE(buf ^ 1, e0B, e1B);
            const int tn2 = (t + 8 < t1) ? t + 8 : ((t + 4 < t1) ? t + 4 : t);
            const int e0N = tiles[(tn2 << 4) + srow];
            const int e1N = tiles[(tn2 << 4) + 8 + srow];

            const int kk = (__builtin_amdgcn_readfirstlane(e0A) >> 22) & 31;
            const short8* wp = (const short8*)Wb2 + (size_t)(kk * 4) * 64 + lane;
            const short8 f00 = wp[0], f01 = wp[64], f10 = wp[128], f11 = wp[192];

            // allow {STAGE(t+4) x2, er(t+8) x2} outstanding
            asm volatile("s_waitcnt vmcnt(4)" ::: "memory");
            __builtin_amdgcn_sched_barrier(0);

            const short8 a0 = *(const short8*)&stg[wave][buf][r * 64 + g * 8];
            const short8 a1 = *(const short8*)&stg[wave][buf][r * 64 + 32 + g * 8];

            f32x4 acc0 = {}, acc1 = {};
            acc0 = __builtin_amdgcn_mfma_f32_16x16x32_bf16(a0, f00, acc0, 0, 0, 0);
            acc0 = __builtin_amdgcn_mfma_f32_16x16x32_bf16(a1, f01, acc0, 0, 0, 0);
            acc1 = __builtin_amdgcn_mfma_f32_16x16x32_bf16(a0, f10, acc1, 0, 0, 0);
            acc1 = __builtin_amdgcn_mfma_f32_16x16x32_bf16(a1, f11, acc1, 0, 0, 0);

#pragma unroll
            for (int i = 0; i < 4; ++i) {
                const int rm = tiles[(t << 4) + g * 4 + i];
                if ((rm >> 27) & 1) {
                    float* op = &ow[((rm >> 18) & 15) * 36 + r];
                    atomicAdd(op +  0, acc0[i]);
                    atomicAdd(op + 16, acc1[i]);
                }
            }
            e0A = e0B; e1A = e1B; e0B = e0N; e1B = e1N; buf ^= 1;
        }
    }
#undef C2_STAGE

    __syncthreads();
    float* optr = out + (size_t)G * VT * C_OUT;
    for (int i = tid; i < VT * C_OUT; i += 256) {
        const int i0 = (i >> 5) * 36 + (i & 31);
        optr[i] = os[0][i0] + os[1][i0] + os[2][i0] + os[3][i0];
    }
}

// ---------------------------------------------------------------------------
extern "C" void kernel_launch(void* const* d_in, const int* in_sizes, int n_in,
                              void* d_out, int out_size, void* d_ws, size_t ws_size,
                              hipStream_t stream) {
    const float* feats   = (const float*)d_in[0];
    const int*   in_idx  = (const int*)  d_in[1];
    const int*   out_idx = (const int*)  d_in[2];
    const float* mask    = (const float*)d_in[3];
    const float* W_in    = (const float*)d_in[4];
    const float* W_out   = (const float*)d_in[5];
    float* out = (float*)d_out;

    // ws layout (bytes)
    char* ws = (char*)d_ws;
    unsigned short* h      = (unsigned short*)(ws);               // 25,600,000
    unsigned short* featsb = (unsigned short*)(ws + 25600000);    // 12,800,000
    short* Wb1   = (short*)(ws + 38400000);                       //    131,072
    short* Wb2   = (short*)(ws + 38531072);                       //    131,072
    int*   tiles = (int*)  (ws + 38662144);                       // 63,500,000
    int*   counts= (int*)  (ws + 102162144);                      //  1,350,048
    int*   off   = (int*)  (ws + 103512192);                      //  1,350,016
    int*   cursor= (int*)  (ws + 104862208);                      //  1,350,000
    int*   bsum  = (int*)  (ws + 106212208);                      //      5,276

    hipMemsetAsync(counts, 0, NBUCK * sizeof(int), stream);
    hipMemsetAsync(tiles,  0, 63500000, stream);                  // padding -> valid=0

    cvt_feats<<<N_VOX * C_IN / 4 / 256, 256, 0, stream>>>(feats, featsb);
    cvt_w<<<216, 64, 0, stream>>>(W_in, W_out, Wb1, Wb2);

    const int nblk = (NPAIR_TOT + 255) / 256;
    count_kernel<<<nblk, 256, 0, stream>>>(out_idx, mask, counts);
    scan_a<<<NSB, 256, 0, stream>>>(counts, bsum);
    scan_b<<<1,   256, 0, stream>>>(bsum);
    scan_c<<<NSB, 256, 0, stream>>>(counts, bsum, off, cursor);
    fill_kernel<<<nblk, 256, 0, stream>>>(in_idx, out_idx, mask, cursor, tiles);

    conv1_tile<<<NGRP, 256, 0, stream>>>(featsb, Wb1, tiles, off, h);
    conv2_tile<<<NGRP, 256, 0, stream>>>(h, Wb2, tiles, off, out);
}

// Round 10
// 934.789 us; speedup vs baseline: 3.4656x; 3.4656x over previous
//
#include <hip/hip_runtime.h>

#define N_VOX 200000
#define K_OFF 27
#define P_PAIR 400000
#define C_IN 32
#define C_MID 64
#define C_OUT 32
#define PPB 320            // 4 waves x 5 tiles x 16 pairs; 400000 % 320 == 0
#define TILES_PER_WAVE 5

typedef __attribute__((ext_vector_type(8))) short short8;
typedef __attribute__((ext_vector_type(4))) float f32x4;
typedef __attribute__((ext_vector_type(4))) unsigned int u32x4;

__device__ inline unsigned short f2bf(float f) {
    union { float f; unsigned u; } v; v.f = f;
    unsigned r = v.u + 0x7FFF + ((v.u >> 16) & 1);   // RNE
    return (unsigned short)(r >> 16);
}

// packed bf16 atomic: mem[p] += lo, mem[p+1] += hi  (one TCC atomic op)
__device__ inline void pk_add_bf16(unsigned short* p, float lo, float hi) {
    const unsigned d = (unsigned)f2bf(lo) | ((unsigned)f2bf(hi) << 16);
    asm volatile("global_atomic_pk_add_bf16 %0, %1, off" :: "v"(p), "v"(d) : "memory");
}

// ---------- feats f32 -> bf16 (12.8 MB) ----------
__global__ __launch_bounds__(256) void cvt_feats(
    const float* __restrict__ in, unsigned short* __restrict__ out)
{
    const int i = blockIdx.x * 256 + threadIdx.x;    // grid exact: 6250 blocks
    f32x4 v = ((const f32x4*)in)[i];
    ((unsigned int*)out)[2*i]   = (unsigned)f2bf(v[0]) | ((unsigned)f2bf(v[1]) << 16);
    ((unsigned int*)out)[2*i+1] = (unsigned)f2bf(v[2]) | ((unsigned)f2bf(v[3]) << 16);
}

// ---------- W -> fragment tables with PK-friendly column permutation ------
// conv1 frag (k,nt), lane(g,r), j: col = 2r + (nt&1) + 32*(nt>>1), row = g*8+j
//   -> lane acc pairs (nt0,nt1)=(ch 2r,2r+1), (nt2,nt3)=(ch 32+2r,33+2r)
// conv2 frag (k,nt,ks): col = 2r + nt, row = ks*32 + g*8 + j
__global__ __launch_bounds__(64) void cvt_w(
    const float* __restrict__ W_in, const float* __restrict__ W_out,
    short* __restrict__ Wb1, short* __restrict__ Wb2)
{
    const int b = blockIdx.x, lane = threadIdx.x;
    const int g = lane >> 4, r = lane & 15;
    short8 o;
    if (b < 108) {                                   // conv1: k=b>>2, nt=b&3
        const int k = b >> 2, nt = b & 3;
        const int col = 2 * r + (nt & 1) + 32 * (nt >> 1);
        const float* Wk = W_in + (size_t)k * (C_IN * C_MID);
#pragma unroll
        for (int j = 0; j < 8; ++j) o[j] = (short)f2bf(Wk[(g*8+j)*C_MID + col]);
        *(short8*)(Wb1 + (size_t)(b * 64 + lane) * 8) = o;
    } else {                                         // conv2: q=nt*2+ks
        const int b2 = b - 108, k = b2 >> 2, q = b2 & 3;
        const int nt = q >> 1, ks = q & 1;
        const int col = 2 * r + nt;
        const float* Wk = W_out + (size_t)k * (C_MID * C_OUT);
#pragma unroll
        for (int j = 0; j < 8; ++j) o[j] = (short)f2bf(Wk[(ks*32 + g*8 + j)*C_OUT + col]);
        *(short8*)(Wb2 + (size_t)(b2 * 64 + lane) * 8) = o;
    }
}

// ---------- conv1: R3 streaming structure, pk-bf16 scatter ----------
// MFMA 16x16x32 bf16; A: lane(g,r) = pair pbase+r, ch g*8..+7 (one short8).
// C/D row m=4g+i (pair), "col" r -> channels via permutation above.
__global__ __launch_bounds__(256) void conv1_mfma(
    const unsigned short* __restrict__ featsb,
    const int*   __restrict__ in_idx,
    const int*   __restrict__ out_idx,
    const float* __restrict__ mask,
    const short* __restrict__ Wb1,
    unsigned short* __restrict__ h)
{
    const int k    = blockIdx.x;
    const int lane = threadIdx.x & 63;
    const int wave = threadIdx.x >> 6;
    const int g    = lane >> 4;
    const int r    = lane & 15;
    const size_t koff = (size_t)k * P_PAIR;

    const short8* wp = (const short8*)Wb1 + (size_t)(k * 4) * 64 + lane;
    const short8 f0 = wp[0], f1 = wp[64], f2 = wp[128], f3 = wp[192];

    const int wbase = blockIdx.y * PPB + wave * (PPB / 4);
#pragma unroll 1
    for (int t = 0; t < TILES_PER_WAVE; ++t) {
        const int pbase = wbase + t * 16;
        const int pr = pbase + r;
        const bool avalid = (mask[koff + pr] > 0.5f);

        short8 a = {};
        if (avalid)
            a = *(const short8*)(featsb + (size_t)in_idx[koff + pr] * C_IN + g * 8);

        f32x4 acc0 = {}, acc1 = {}, acc2 = {}, acc3 = {};
        acc0 = __builtin_amdgcn_mfma_f32_16x16x32_bf16(a, f0, acc0, 0, 0, 0);
        acc1 = __builtin_amdgcn_mfma_f32_16x16x32_bf16(a, f1, acc1, 0, 0, 0);
        acc2 = __builtin_amdgcn_mfma_f32_16x16x32_bf16(a, f2, acc2, 0, 0, 0);
        acc3 = __builtin_amdgcn_mfma_f32_16x16x32_bf16(a, f3, acc3, 0, 0, 0);

#pragma unroll
        for (int i = 0; i < 4; ++i) {
            const int m = g * 4 + i;                 // this lane's C/D rows
            const size_t e = koff + pbase + m;
            if (mask[e] > 0.5f) {                    // ground-truth re-read
                unsigned short* hp = h + (size_t)out_idx[e] * C_MID + 2 * r;
                pk_add_bf16(hp,      acc0[i], acc1[i]);   // ch 2r, 2r+1
                pk_add_bf16(hp + 32, acc2[i], acc3[i]);   // ch 32+2r, 33+2r
            }
        }
    }
}

// ---------- ReLU on h (bf16, bit-trick, in place) ----------
__global__ __launch_bounds__(256) void relu_h(unsigned int* __restrict__ h)
{
    const int i = blockIdx.x * 256 + threadIdx.x;    // grid exact: 6250 blocks
    u32x4 v = ((u32x4*)h)[i];
#pragma unroll
    for (int c = 0; c < 4; ++c) {
        unsigned m = v[c] & 0x80008000u;             // sign bits per half
        m |= m >> 1; m |= m >> 2; m |= m >> 4; m |= m >> 8;  // spread to 0xFFFF
        v[c] &= ~m;                                  // negative halves -> +0
    }
    ((u32x4*)h)[i] = v;
}

// ---------- conv2: K=64 (2 k-steps), pk-bf16 scatter into out_ws ----------
__global__ __launch_bounds__(256) void conv2_mfma(
    const unsigned short* __restrict__ hb,
    const int*   __restrict__ in_idx,
    const int*   __restrict__ out_idx,
    const float* __restrict__ mask,
    const short* __restrict__ Wb2,
    unsigned short* __restrict__ outw)
{
    const int k    = blockIdx.x;
    const int lane = threadIdx.x & 63;
    const int wave = threadIdx.x >> 6;
    const int g    = lane >> 4;
    const int r    = lane & 15;
    const size_t koff = (size_t)k * P_PAIR;

    const short8* wp = (const short8*)Wb2 + (size_t)(k * 4) * 64 + lane;
    const short8 f00 = wp[0], f01 = wp[64], f10 = wp[128], f11 = wp[192];

    const int wbase = blockIdx.y * PPB + wave * (PPB / 4);
#pragma unroll 1
    for (int t = 0; t < TILES_PER_WAVE; ++t) {
        const int pbase = wbase + t * 16;
        const int pr = pbase + r;
        const bool avalid = (mask[koff + pr] > 0.5f);

        short8 a0 = {}, a1 = {};
        if (avalid) {
            const short8* row = (const short8*)(hb + (size_t)in_idx[koff + pr] * C_MID);
            a0 = row[g];                             // ch g*8..+7   (k-step 0)
            a1 = row[4 + g];                         // ch 32+g*8..  (k-step 1)
        }

        f32x4 acc0 = {}, acc1 = {};
        acc0 = __builtin_amdgcn_mfma_f32_16x16x32_bf16(a0, f00, acc0, 0, 0, 0);
        acc0 = __builtin_amdgcn_mfma_f32_16x16x32_bf16(a1, f01, acc0, 0, 0, 0);
        acc1 = __builtin_amdgcn_mfma_f32_16x16x32_bf16(a0, f10, acc1, 0, 0, 0);
        acc1 = __builtin_amdgcn_mfma_f32_16x16x32_bf16(a1, f11, acc1, 0, 0, 0);

#pragma unroll
        for (int i = 0; i < 4; ++i) {
            const int m = g * 4 + i;
            const size_t e = koff + pbase + m;
            if (mask[e] > 0.5f) {
                unsigned short* op = outw + (size_t)out_idx[e] * C_OUT + 2 * r;
                pk_add_bf16(op, acc0[i], acc1[i]);   // ch 2r, 2r+1
            }
        }
    }
}

// ---------- out_ws bf16 -> d_out f32 ----------
__global__ __launch_bounds__(256) void cvt_out(
    const unsigned int* __restrict__ outw, float* __restrict__ out)
{
    const int i = blockIdx.x * 256 + threadIdx.x;    // grid exact: 6250 blocks
    const unsigned v0 = outw[2 * i], v1 = outw[2 * i + 1];
    union { unsigned u; float f; } a, b, c, d;
    a.u = v0 << 16; b.u = v0 & 0xFFFF0000u;
    c.u = v1 << 16; d.u = v1 & 0xFFFF0000u;
    f32x4 o = { a.f, b.f, c.f, d.f };
    ((f32x4*)out)[i] = o;
}

// ---------------------------------------------------------------------------
extern "C" void kernel_launch(void* const* d_in, const int* in_sizes, int n_in,
                              void* d_out, int out_size, void* d_ws, size_t ws_size,
                              hipStream_t stream) {
    const float* feats   = (const float*)d_in[0];
    const int*   in_idx  = (const int*)  d_in[1];
    const int*   out_idx = (const int*)  d_in[2];
    const float* mask    = (const float*)d_in[3];
    const float* W_in    = (const float*)d_in[4];
    const float* W_out   = (const float*)d_in[5];
    float* out = (float*)d_out;

    // ws layout (bytes): h_bf16 | feats_bf16 | out_bf16 | Wb1 | Wb2
    char* ws = (char*)d_ws;
    unsigned short* h      = (unsigned short*)(ws);               // 25,600,000
    unsigned short* featsb = (unsigned short*)(ws + 25600000);    // 12,800,000
    unsigned short* outw   = (unsigned short*)(ws + 38400000);    // 12,800,000
    short* Wb1 = (short*)(ws + 51200000);                         //    110,592
    short* Wb2 = (short*)(ws + 51310592);                         //    110,592

    hipMemsetAsync(h,    0, (size_t)N_VOX * C_MID * 2, stream);
    hipMemsetAsync(outw, 0, (size_t)N_VOX * C_OUT * 2, stream);

    cvt_feats<<<N_VOX * C_IN / 4 / 256, 256, 0, stream>>>(feats, featsb);
    cvt_w<<<216, 64, 0, stream>>>(W_in, W_out, Wb1, Wb2);

    dim3 grid(K_OFF, P_PAIR / PPB);                               // (27, 1250)
    conv1_mfma<<<grid, 256, 0, stream>>>(featsb, in_idx, out_idx, mask, Wb1, h);
    relu_h<<<N_VOX * C_MID / 8 / 256, 256, 0, stream>>>((unsigned int*)h);
    conv2_mfma<<<grid, 256, 0, stream>>>(h, in_idx, out_idx, mask, Wb2, outw);
    cvt_out<<<N_VOX * C_OUT / 4 / 256, 256, 0, stream>>>((const unsigned int*)outw, out);
}